// Round 8
// baseline (157.417 us; speedup 1.0000x reference)
//
#include <hip/hip_runtime.h>
#include <hip/hip_bf16.h>

#define B_   64
#define H_   1024
#define E_   512
#define V_   50000
#define S_   400
#define EXTV 50100        // V + 100
#define K2   2048         // 2H
#define KP   2560         // 2H + E
#define VP   50016        // padded e row stride (multiple of 16)
#define NBLK 782          // ceil(V / 64)
#define PSTR 800          // padded partial-sum stride
#define KCH  16           // split-K chunks for mid GEMM
#define WSL  8192         // W LDS slice bytes (64 cols x 32 f32)
#define ASL  4096         // A LDS slice bytes (64 rows x 32 bf16)

typedef float  f32x4  __attribute__((ext_vector_type(4)));
typedef __bf16 bf16x8 __attribute__((ext_vector_type(8)));

typedef __attribute__((address_space(1))) const void gas_t;
typedef __attribute__((address_space(3))) void las_t;
#define GLL16(g, l) __builtin_amdgcn_global_load_lds((gas_t*)(g), (las_t*)(l), 16, 0, 0)

// asm global load: 16B into dst, base VGPR-pair + literal byte offset.
#define GLD(dst, base, imm)                                                     \
    asm volatile("global_load_dwordx4 %0, %1, off offset:%2"                    \
                 : "=v"(dst) : "v"(base), "n"(imm) : "memory")

static __device__ __forceinline__ bf16x8 pack_bf16(f32x4 a, f32x4 b) {
    bf16x8 r;
    r[0] = (__bf16)a[0]; r[1] = (__bf16)a[1]; r[2] = (__bf16)a[2]; r[3] = (__bf16)a[3];
    r[4] = (__bf16)b[0]; r[5] = (__bf16)b[1]; r[6] = (__bf16)b[2]; r[7] = (__bf16)b[3];
    return r;
}

// ================= PROBES (read-only; results go to dead ws region) =========
// probeA: fully linear coalesced streaming read, 144 MB of Wv.
__global__ __launch_bounds__(256) void k_probeA(const float* __restrict__ Wv,
                                                float* __restrict__ dummy) {
    int gid = blockIdx.x * 256 + threadIdx.x;           // grid = NBLK -> 200192 thr
    const f32x4* p = (const f32x4*)Wv;
    float s = 0.f;
    for (int j = 0; j < 45; ++j) {                      // 45 * 3.2MB = 144 MB
        f32x4 v = p[(size_t)j * 200192 + gid];
        s += v[0] + v[1] + v[2] + v[3];
    }
    dummy[gid] = s;
}

// probeB: R3's DMA staging loop with compute stripped. Fragmented 128B/row
// global_load_lds, depth-3 pipeline, counted vmcnt, barrier per slice.
// 22 slices x 8KB x 782 blocks = 137.6 MB.
__global__ __launch_bounds__(256, 3) void k_probeB(const float* __restrict__ Wv,
                                                   float* __restrict__ dummy) {
    __shared__ __align__(16) char ldsW[4 * WSL];
    int tid = threadIdx.x, wave = tid >> 6, lane = tid & 63;
    int colBase = blockIdx.x * 64;
    int c1 = colBase + wave * 8 + (lane >> 3);
    int c2 = c1 + 32;
    if (c1 >= V_) c1 = V_ - 1;
    if (c2 >= V_) c2 = V_ - 1;
    int tsw = (((lane & 7) ^ (lane >> 3)) << 4);
    const char* srcW1 = (const char*)Wv + (size_t)c1 * 4096 + tsw;
    const char* srcW2 = (const char*)Wv + (size_t)c2 * 4096 + tsw;
    char* dW1 = ldsW + wave * 1024;
    char* dW2 = ldsW + 4096 + wave * 1024;
    int w_off0 = (wave * 16 + (lane & 15)) * 128;
    float s = 0.f;
#pragma unroll
    for (int q = 0; q < 3; ++q) {
        GLL16(srcW1 + q * 128, dW1 + q * WSL);
        GLL16(srcW2 + q * 128, dW2 + q * WSL);
    }
#define PB(i, N) do {                                                           \
        asm volatile("s_waitcnt vmcnt(" #N ")" ::: "memory");                   \
        __builtin_amdgcn_s_barrier();                                           \
        if ((i) + 3 < 22) {                                                     \
            GLL16(srcW1 + ((i) + 3) * 128, dW1 + (((i) + 3) & 3) * WSL);        \
            GLL16(srcW2 + ((i) + 3) * 128, dW2 + (((i) + 3) & 3) * WSL);        \
        }                                                                       \
        f32x4 w0 = *(const f32x4*)(ldsW + ((i) & 3) * WSL + w_off0);            \
        s += w0[0] + w0[1] + w0[2] + w0[3];                                     \
    } while (0)
    PB(0, 4);  PB(1, 4);  PB(2, 4);  PB(3, 4);  PB(4, 4);  PB(5, 4);
    PB(6, 4);  PB(7, 4);  PB(8, 4);  PB(9, 4);  PB(10, 4); PB(11, 4);
    PB(12, 4); PB(13, 4); PB(14, 4); PB(15, 4); PB(16, 4); PB(17, 4);
    PB(18, 4); PB(19, 4); PB(20, 2); PB(21, 0);
#undef PB
    dummy[blockIdx.x * 256 + tid] = s;
}

// probeC: fragmented plain vector loads (16 rows per instr, 128B/row), drained
// per 512B-burst. 6 bursts x 512B x 64 rows x 782 blocks = 150 MB.
__global__ __launch_bounds__(256) void k_probeC(const float* __restrict__ Wv,
                                                float* __restrict__ dummy) {
    int tid = threadIdx.x, wave = tid >> 6, lane = tid & 63;
    int lr = lane & 15, lg = lane >> 4;
    int col = blockIdx.x * 64 + wave * 16 + lr;
    if (col >= V_) col = V_ - 1;
    const char* baseW = (const char*)(Wv + (size_t)col * H_ + lg * 8);
    float s = 0.f;
    f32x4 w0, w1, w2, w3;
#define PC(c) do {                                                              \
        GLD(w0, baseW + (c) * 512, 0);   GLD(w1, baseW + (c) * 512, 128);       \
        GLD(w2, baseW + (c) * 512, 256); GLD(w3, baseW + (c) * 512, 384);       \
        asm volatile("s_waitcnt vmcnt(0)" ::: "memory");                        \
        s += w0[0] + w0[3] + w1[0] + w1[3] + w2[0] + w2[3] + w3[0] + w3[3];     \
    } while (0)
    PC(0); PC(1); PC(2); PC(3); PC(4); PC(5);
#undef PC
    dummy[blockIdx.x * 256 + tid] = s;
}

// ---------------- p_gen: 64 dots of length 2560 -----------------------------
__global__ __launch_bounds__(256) void k_pgen(const float* __restrict__ dec,
                                              const float* __restrict__ ctx,
                                              const float* __restrict__ emb,
                                              const float* __restrict__ Wp,
                                              const float* __restrict__ bp,
                                              float* __restrict__ pg,
                                              float* __restrict__ out1) {
    int b = blockIdx.x;
    int tid = threadIdx.x;
    float s = 0.f;
    for (int k = tid; k < KP; k += 256) {
        float x;
        if (k < H_)          x = dec[b * H_ + k];
        else if (k < 2 * H_) x = ctx[b * H_ + k - H_];
        else                 x = emb[b * E_ + k - 2 * H_];
        s += x * Wp[k];
    }
#pragma unroll
    for (int m = 32; m >= 1; m >>= 1) s += __shfl_xor(s, m);
    __shared__ float r[4];
    int wave = tid >> 6, lane = tid & 63;
    if (lane == 0) r[wave] = s;
    __syncthreads();
    if (tid == 0) {
        float t = r[0] + r[1] + r[2] + r[3] + bp[0];
        float p = 1.f / (1.f + __expf(-t));
        pg[b]   = p;
        out1[b] = p;
    }
}

// ---------------- mid GEMM (split-K 16): M=64, N=1024, K=2048 ---------------
__global__ __launch_bounds__(256, 4) void k_gemm_mid(const float* __restrict__ dec,
                                                     const float* __restrict__ ctx,
                                                     const float* __restrict__ Wm,
                                                     float* __restrict__ pmid) {
    int nt   = blockIdx.x;             // 0..15  (h-tile of 64)
    int kc   = blockIdx.y;             // 0..15  (K-chunk of 128)
    int wave = threadIdx.x >> 6;
    int lane = threadIdx.x & 63;
    int lr   = lane & 15, lg = lane >> 4;
    int col  = nt * 64 + wave * 16 + lr;          // h index
    const float* xb   = (kc < 8) ? dec : ctx;
    int kbase         = (kc & 7) * 128;
    const float* wrow = Wm + (size_t)col * K2 + kc * 128 + lg * 8;
    const float* xrow = xb + (size_t)lr * H_ + kbase + lg * 8;

    f32x4 w0s[4], w1s[4];
#pragma unroll
    for (int p = 0; p < 4; ++p) {
        w0s[p] = *(const f32x4*)(wrow + p * 32);
        w1s[p] = *(const f32x4*)(wrow + p * 32 + 4);
    }
    f32x4 acc[4] = {};
#pragma unroll
    for (int i = 0; i < 4; ++i) {
        f32x4 a0[4], a1[4];
#pragma unroll
        for (int mf = 0; mf < 4; ++mf) {
            const float* xp = xrow + (size_t)(mf * 16) * H_ + i * 32;
            a0[mf] = *(const f32x4*)xp;
            a1[mf] = *(const f32x4*)(xp + 4);
        }
        bf16x8 bf = pack_bf16(w0s[i], w1s[i]);
#pragma unroll
        for (int mf = 0; mf < 4; ++mf) {
            bf16x8 af = pack_bf16(a0[mf], a1[mf]);
            acc[mf] = __builtin_amdgcn_mfma_f32_16x16x32_bf16(af, bf, acc[mf], 0, 0, 0);
        }
    }
#pragma unroll
    for (int mf = 0; mf < 4; ++mf)
#pragma unroll
        for (int r = 0; r < 4; ++r) {
            int row = mf * 16 + lg * 4 + r;       // batch index
            pmid[((size_t)kc * B_ + row) * H_ + col] = acc[mf][r];
        }
}

// ---------------- reduce split-K partials, bias, tanh, -> bf16 --------------
__global__ __launch_bounds__(256) void k_mid_reduce(const float* __restrict__ pmid,
                                                    const float* __restrict__ bm,
                                                    __bf16* __restrict__ midb) {
    int idx = blockIdx.x * 256 + threadIdx.x;     // 65536
    int h = idx & (H_ - 1);
    int m = idx >> 10;
    float s = bm[h];
#pragma unroll
    for (int kc = 0; kc < KCH; ++kc) s += pmid[((size_t)kc * B_ + m) * H_ + h];
    midb[idx] = (__bf16)tanhf(s);
}

// ---------------- big GEMM (R3 verbatim — timed best) -----------------------
__global__ __launch_bounds__(256, 3) void k_gemm_vocab(const __bf16* __restrict__ midb,
                                                       const float* __restrict__ Wv,
                                                       const float* __restrict__ bv,
                                                       float* __restrict__ e,
                                                       float* __restrict__ psum) {
    __shared__ __align__(16) char ldsW[4 * WSL];   // 32 KB
    __shared__ __align__(16) char ldsA[4 * ASL];   // 16 KB
    int tid  = threadIdx.x;
    int wave = tid >> 6;
    int lane = tid & 63;
    int lr   = lane & 15, lg = lane >> 4;
    int blk  = blockIdx.x;
    int colBase = blk * 64;

    int c1 = colBase + wave * 8 + (lane >> 3);         // W chunk a: cols 0..31
    int c2 = c1 + 32;                                  // W chunk b: cols 32..63
    if (c1 >= V_) c1 = V_ - 1;
    if (c2 >= V_) c2 = V_ - 1;
    int tsw = (((lane & 7) ^ (lane >> 3)) << 4);       // (t ^ (col&7))*16 bytes
    const char* srcW1 = (const char*)Wv + (size_t)c1 * 4096 + tsw;
    const char* srcW2 = (const char*)Wv + (size_t)c2 * 4096 + tsw;
    int arow = wave * 16 + (lane >> 2);                // A: row per lane
    int asw  = (((lane & 3) ^ ((lane >> 3) & 3)) << 4);// (s ^ phi(row))*16 bytes
    const char* srcA = (const char*)midb + (size_t)arow * 2048 + asw;

    char* dW1 = ldsW + wave * 1024;
    char* dW2 = ldsW + 4096 + wave * 1024;
    char* dA  = ldsA + wave * 1024;

    int col    = wave * 16 + lr;                       // block-local vocab col
    int w_off0 = col * 128 + ((((lg * 2)     ) ^ (lr & 7)) << 4);
    int w_off1 = col * 128 + ((((lg * 2) + 1 ) ^ (lr & 7)) << 4);
    int phiA   = (lr >> 1) & 3;
    int aoff0  = (0 * 16 + lr) * 64 + ((lg ^ phiA) << 4);
    int aoff1  = (1 * 16 + lr) * 64 + ((lg ^ phiA) << 4);
    int aoff2  = (2 * 16 + lr) * 64 + ((lg ^ phiA) << 4);
    int aoff3  = (3 * 16 + lr) * 64 + ((lg ^ phiA) << 4);

    f32x4 acc0 = {}, acc1 = {}, acc2 = {}, acc3 = {};

#pragma unroll
    for (int s = 0; s < 3; ++s) {
        GLL16(srcW1 + s * 128, dW1 + s * WSL);
        GLL16(srcW2 + s * 128, dW2 + s * WSL);
        GLL16(srcA  + s * 64,  dA  + s * ASL);
    }

#define VBODY(i, N) do {                                                        \
        __builtin_amdgcn_sched_barrier(0);                                      \
        asm volatile("s_waitcnt vmcnt(" #N ")" ::: "memory");                   \
        __builtin_amdgcn_s_barrier();                                           \
        if ((i) + 3 < 32) {                                                     \
            GLL16(srcW1 + ((i) + 3) * 128, dW1 + (((i) + 3) & 3) * WSL);        \
            GLL16(srcW2 + ((i) + 3) * 128, dW2 + (((i) + 3) & 3) * WSL);        \
            GLL16(srcA  + ((i) + 3) * 64,  dA  + (((i) + 3) & 3) * ASL);        \
        }                                                                       \
        const char* wS = ldsW + ((i) & 3) * WSL;                                \
        const char* aS = ldsA + ((i) & 3) * ASL;                                \
        f32x4 w0 = *(const f32x4*)(wS + w_off0);                                \
        f32x4 w1 = *(const f32x4*)(wS + w_off1);                                \
        bf16x8 bfr = pack_bf16(w0, w1);                                         \
        bf16x8 af0 = *(const bf16x8*)(aS + aoff0);                              \
        bf16x8 af1 = *(const bf16x8*)(aS + aoff1);                              \
        bf16x8 af2 = *(const bf16x8*)(aS + aoff2);                              \
        bf16x8 af3 = *(const bf16x8*)(aS + aoff3);                              \
        acc0 = __builtin_amdgcn_mfma_f32_16x16x32_bf16(af0, bfr, acc0, 0, 0, 0);\
        acc1 = __builtin_amdgcn_mfma_f32_16x16x32_bf16(af1, bfr, acc1, 0, 0, 0);\
        acc2 = __builtin_amdgcn_mfma_f32_16x16x32_bf16(af2, bfr, acc2, 0, 0, 0);\
        acc3 = __builtin_amdgcn_mfma_f32_16x16x32_bf16(af3, bfr, acc3, 0, 0, 0);\
    } while (0)

    VBODY(0, 6);  VBODY(1, 6);  VBODY(2, 6);  VBODY(3, 6);
    VBODY(4, 6);  VBODY(5, 6);  VBODY(6, 6);  VBODY(7, 6);
    VBODY(8, 6);  VBODY(9, 6);  VBODY(10, 6); VBODY(11, 6);
    VBODY(12, 6); VBODY(13, 6); VBODY(14, 6); VBODY(15, 6);
    VBODY(16, 6); VBODY(17, 6); VBODY(18, 6); VBODY(19, 6);
    VBODY(20, 6); VBODY(21, 6); VBODY(22, 6); VBODY(23, 6);
    VBODY(24, 6); VBODY(25, 6); VBODY(26, 6); VBODY(27, 6);
    VBODY(28, 6); VBODY(29, 6); VBODY(30, 3); VBODY(31, 0);
#undef VBODY

    int gcol = colBase + col;
    bool valid = gcol < V_;
    float bias = valid ? bv[valid ? gcol : V_ - 1] : 0.f;
    __shared__ float wsum[4][64];
    f32x4 accs[4] = {acc0, acc1, acc2, acc3};
#pragma unroll
    for (int mf = 0; mf < 4; ++mf) {
#pragma unroll
        for (int r = 0; r < 4; ++r) {
            int row = mf * 16 + lg * 4 + r;       // batch index
            float logit = accs[mf][r] + bias;
            logit = fminf(fmaxf(logit, -50.f), 50.f);
            float ev = valid ? __expf(logit - 50.f) : 0.f;
            if (valid) e[(size_t)row * VP + gcol] = ev;
            float s = ev;
            s += __shfl_xor(s, 1); s += __shfl_xor(s, 2);
            s += __shfl_xor(s, 4); s += __shfl_xor(s, 8);
            if (lr == 0) wsum[wave][row] = s;
        }
    }
    __syncthreads();
    if (threadIdx.x < 64) {
        int row = threadIdx.x;
        float t = wsum[0][row] + wsum[1][row] + wsum[2][row] + wsum[3][row];
        psum[(size_t)row * PSTR + blk] = t;
    }
}

// ---------------- Z reduction: zinv[b] = 1 / sum_blk psum ------------------
__global__ __launch_bounds__(256) void k_zred(const float* __restrict__ psum,
                                              float* __restrict__ zinv) {
    int b = blockIdx.x;
    int tid = threadIdx.x;
    float s = 0.f;
    for (int i = tid; i < NBLK; i += 256) s += psum[(size_t)b * PSTR + i];
#pragma unroll
    for (int m = 32; m >= 1; m >>= 1) s += __shfl_xor(s, m);
    __shared__ float r[4];
    int wave = tid >> 6, lane = tid & 63;
    if (lane == 0) r[wave] = s;
    __syncthreads();
    if (tid == 0) zinv[b] = 1.f / (r[0] + r[1] + r[2] + r[3]);
}

// ---------------- vocab_dist + generation part of final_dist ---------------
__global__ __launch_bounds__(256) void k_final(const float* __restrict__ e,
                                               const float* __restrict__ zinv,
                                               const float* __restrict__ pg,
                                               float* __restrict__ out0,
                                               float* __restrict__ out2) {
    int idx = blockIdx.x * 256 + threadIdx.x;     // < 64*50100
    if (idx >= B_ * EXTV) return;
    int b = idx / EXTV;
    int v = idx - b * EXTV;
    float o = 0.f;
    if (v < V_) {
        float vd = e[(size_t)b * VP + v] * zinv[b];
        out2[(size_t)b * V_ + v] = vd;
        o = pg[b] * vd;
    }
    out0[idx] = o;
}

// ---------------- copy-distribution scatter --------------------------------
__global__ __launch_bounds__(256) void k_scatter(const float* __restrict__ attn,
                                                 const int* __restrict__ sid,
                                                 const int* __restrict__ oov,
                                                 const float* __restrict__ pg,
                                                 float* __restrict__ out0) {
    int idx = blockIdx.x * 256 + threadIdx.x;
    if (idx >= B_ * S_) return;
    int b = idx / S_;
    int m = oov[idx];
    int tgt = (m >= 0) ? (V_ + m) : sid[idx];
    float w = (1.f - pg[b]) * attn[idx];
    atomicAdd(out0 + (size_t)b * EXTV + tgt, w);
}

extern "C" void kernel_launch(void* const* d_in, const int* in_sizes, int n_in,
                              void* d_out, int out_size, void* d_ws, size_t ws_size,
                              hipStream_t stream) {
    const float* dec  = (const float*)d_in[0];
    const float* ctx  = (const float*)d_in[1];
    const float* emb  = (const float*)d_in[2];
    const float* attn = (const float*)d_in[3];
    const int*   sid  = (const int*)d_in[4];
    const int*   oov  = (const int*)d_in[5];
    // d_in[6] = vocab_size (known statically = 50000)
    const float* Wm   = (const float*)d_in[7];
    const float* bm   = (const float*)d_in[8];
    const float* Wp   = (const float*)d_in[9];
    const float* bp   = (const float*)d_in[10];
    const float* Wv   = (const float*)d_in[11];
    const float* bv   = (const float*)d_in[12];

    float* out0 = (float*)d_out;                  // final_dist [64][50100]
    float* out1 = out0 + (size_t)B_ * EXTV;       // p_gen      [64]
    float* out2 = out1 + B_;                      // vocab_dist [64][50000]

    float*  e    = (float*)d_ws;                  // [64][VP]
    float*  psum = e + (size_t)B_ * VP;           // [64][PSTR]
    float*  zinv = psum + (size_t)B_ * PSTR;      // [64]
    float*  pg   = zinv + 64;                     // [64]
    float*  pmid = pg + 64;                       // [KCH][64][1024]
    __bf16* midb = (__bf16*)(pmid + (size_t)KCH * B_ * H_); // [64][1024]

    // dead scratch for probe results: take the tail of ws (ws is large; the
    // harness's 800MB poison fill shows its true size), 256B-aligned.
    size_t doff = (ws_size > (size_t)64 << 20)
                    ? ((ws_size - ((size_t)4 << 20)) & ~(size_t)255)
                    : ((size_t)40 << 20);
    float* dummy = (float*)((char*)d_ws + doff);

    k_probeA<<<NBLK, 256, 0, stream>>>(Wv, dummy);
    k_probeB<<<NBLK, 256, 0, stream>>>(Wv, dummy);
    k_probeC<<<NBLK, 256, 0, stream>>>(Wv, dummy);

    k_pgen<<<B_, 256, 0, stream>>>(dec, ctx, emb, Wp, bp, pg, out1);
    dim3 gmid(16, KCH);
    k_gemm_mid<<<gmid, 256, 0, stream>>>(dec, ctx, Wm, pmid);
    k_mid_reduce<<<(B_ * H_) / 256, 256, 0, stream>>>(pmid, bm, midb);
    k_gemm_vocab<<<NBLK, 256, 0, stream>>>((const __bf16*)midb, Wv, bv, e, psum);
    k_zred<<<B_, 256, 0, stream>>>(psum, zinv);
    k_final<<<(B_ * EXTV + 255) / 256, 256, 0, stream>>>(e, zinv, pg, out0, out2);
    k_scatter<<<(B_ * S_ + 255) / 256, 256, 0, stream>>>(attn, sid, oov, pg, out0);
}

// Round 9
// 106.542 us; speedup vs baseline: 1.4775x; 1.4775x over previous
//
#include <hip/hip_runtime.h>
#include <hip/hip_bf16.h>

#define B_   64
#define H_   1024
#define E_   512
#define V_   50000
#define S_   400
#define EXTV 50100        // V + 100
#define K2   2048         // 2H
#define KP   2560         // 2H + E
#define VP   50016        // padded e row stride (multiple of 16)
#define NBLK 782          // ceil(V / 64)
#define PSTR 800          // padded partial-sum stride
#define KCH  16           // split-K chunks for mid GEMM
#define WSL  8192         // W LDS slice bytes (64 cols x 32 f32)

typedef float  f32x4  __attribute__((ext_vector_type(4)));
typedef __bf16 bf16x8 __attribute__((ext_vector_type(8)));

typedef __attribute__((address_space(1))) const void gas_t;
typedef __attribute__((address_space(3))) void las_t;
#define GLL16(g, l) __builtin_amdgcn_global_load_lds((gas_t*)(g), (las_t*)(l), 16, 0, 0)

// asm global load: 16B into dst, base VGPR-pair + literal byte offset.
#define GLD(dst, base, imm)                                                     \
    asm volatile("global_load_dwordx4 %0, %1, off offset:%2"                    \
                 : "=v"(dst) : "v"(base), "n"(imm) : "memory")

static __device__ __forceinline__ bf16x8 pack_bf16(f32x4 a, f32x4 b) {
    bf16x8 r;
    r[0] = (__bf16)a[0]; r[1] = (__bf16)a[1]; r[2] = (__bf16)a[2]; r[3] = (__bf16)a[3];
    r[4] = (__bf16)b[0]; r[5] = (__bf16)b[1]; r[6] = (__bf16)b[2]; r[7] = (__bf16)b[3];
    return r;
}

// ---------------- p_gen: 64 dots of length 2560 -----------------------------
__global__ __launch_bounds__(256) void k_pgen(const float* __restrict__ dec,
                                              const float* __restrict__ ctx,
                                              const float* __restrict__ emb,
                                              const float* __restrict__ Wp,
                                              const float* __restrict__ bp,
                                              float* __restrict__ pg,
                                              float* __restrict__ out1) {
    int b = blockIdx.x;
    int tid = threadIdx.x;
    float s = 0.f;
    for (int k = tid; k < KP; k += 256) {
        float x;
        if (k < H_)          x = dec[b * H_ + k];
        else if (k < 2 * H_) x = ctx[b * H_ + k - H_];
        else                 x = emb[b * E_ + k - 2 * H_];
        s += x * Wp[k];
    }
#pragma unroll
    for (int m = 32; m >= 1; m >>= 1) s += __shfl_xor(s, m);
    __shared__ float r[4];
    int wave = tid >> 6, lane = tid & 63;
    if (lane == 0) r[wave] = s;
    __syncthreads();
    if (tid == 0) {
        float t = r[0] + r[1] + r[2] + r[3] + bp[0];
        float p = 1.f / (1.f + __expf(-t));
        pg[b]   = p;
        out1[b] = p;
    }
}

// ---------------- mid GEMM (split-K 16): M=64, N=1024, K=2048 ---------------
__global__ __launch_bounds__(256, 4) void k_gemm_mid(const float* __restrict__ dec,
                                                     const float* __restrict__ ctx,
                                                     const float* __restrict__ Wm,
                                                     float* __restrict__ pmid) {
    int nt   = blockIdx.x;             // 0..15  (h-tile of 64)
    int kc   = blockIdx.y;             // 0..15  (K-chunk of 128)
    int wave = threadIdx.x >> 6;
    int lane = threadIdx.x & 63;
    int lr   = lane & 15, lg = lane >> 4;
    int col  = nt * 64 + wave * 16 + lr;          // h index
    const float* xb   = (kc < 8) ? dec : ctx;
    int kbase         = (kc & 7) * 128;
    const float* wrow = Wm + (size_t)col * K2 + kc * 128 + lg * 8;
    const float* xrow = xb + (size_t)lr * H_ + kbase + lg * 8;

    f32x4 w0s[4], w1s[4];
#pragma unroll
    for (int p = 0; p < 4; ++p) {
        w0s[p] = *(const f32x4*)(wrow + p * 32);
        w1s[p] = *(const f32x4*)(wrow + p * 32 + 4);
    }
    f32x4 acc[4] = {};
#pragma unroll
    for (int i = 0; i < 4; ++i) {
        f32x4 a0[4], a1[4];
#pragma unroll
        for (int mf = 0; mf < 4; ++mf) {
            const float* xp = xrow + (size_t)(mf * 16) * H_ + i * 32;
            a0[mf] = *(const f32x4*)xp;
            a1[mf] = *(const f32x4*)(xp + 4);
        }
        bf16x8 bf = pack_bf16(w0s[i], w1s[i]);
#pragma unroll
        for (int mf = 0; mf < 4; ++mf) {
            bf16x8 af = pack_bf16(a0[mf], a1[mf]);
            acc[mf] = __builtin_amdgcn_mfma_f32_16x16x32_bf16(af, bf, acc[mf], 0, 0, 0);
        }
    }
#pragma unroll
    for (int mf = 0; mf < 4; ++mf)
#pragma unroll
        for (int r = 0; r < 4; ++r) {
            int row = mf * 16 + lg * 4 + r;       // batch index
            pmid[((size_t)kc * B_ + row) * H_ + col] = acc[mf][r];
        }
}

// ---------------- reduce split-K partials, bias, tanh, -> bf16 --------------
__global__ __launch_bounds__(256) void k_mid_reduce(const float* __restrict__ pmid,
                                                    const float* __restrict__ bm,
                                                    __bf16* __restrict__ midb) {
    int idx = blockIdx.x * 256 + threadIdx.x;     // 65536
    int h = idx & (H_ - 1);
    int m = idx >> 10;
    float s = bm[h];
#pragma unroll
    for (int kc = 0; kc < KCH; ++kc) s += pmid[((size_t)kc * B_ + m) * H_ + h];
    midb[idx] = (__bf16)tanhf(s);
}

// ---------------- big GEMM: e = exp(clip(mid @ Wv^T + bv) - 50) -------------
// W path: R3's proven global_load_lds pipeline (depth 4, swizzled, barrier).
// A path: NO LDS-DMA — per-wave register prefetch, depth-3 rotating slots via
// volatile asm (slots indexed by literal (i)%3 -> static). midb then flows
// through L1/L2 (128 KB, fully cache-resident) instead of adding ~100 MB of
// per-block DMA traffic to the fabric.
// FIFO per slice i: issue [A(i+2) x4, W(i+3) x2]; steady wait vmcnt(8)
// retires exactly {W(i), A(i)}. Prologue waits 4,6,8; tail 6,0.
__global__ __launch_bounds__(256, 3) void k_gemm_vocab(const __bf16* __restrict__ midb,
                                                       const float* __restrict__ Wv,
                                                       const float* __restrict__ bv,
                                                       float* __restrict__ e,
                                                       float* __restrict__ psum) {
    __shared__ __align__(16) char ldsW[4 * WSL];   // 32 KB
    int tid  = threadIdx.x;
    int wave = tid >> 6;
    int lane = tid & 63;
    int lr   = lane & 15, lg = lane >> 4;
    int blk  = blockIdx.x;
    int colBase = blk * 64;

    // ---- W staging sources (per-lane, pre-swizzled) ----
    int c1 = colBase + wave * 8 + (lane >> 3);         // W chunk a: cols 0..31
    int c2 = c1 + 32;                                  // W chunk b: cols 32..63
    if (c1 >= V_) c1 = V_ - 1;
    if (c2 >= V_) c2 = V_ - 1;
    int tsw = (((lane & 7) ^ (lane >> 3)) << 4);       // (t ^ (col&7))*16 bytes
    const char* srcW1 = (const char*)Wv + (size_t)c1 * 4096 + tsw;
    const char* srcW2 = (const char*)Wv + (size_t)c2 * 4096 + tsw;
    char* dW1 = ldsW + wave * 1024;
    char* dW2 = ldsW + 4096 + wave * 1024;

    // ---- W LDS read offsets (swizzled) ----
    int col    = wave * 16 + lr;                       // block-local vocab col
    int w_off0 = col * 128 + ((((lg * 2)     ) ^ (lr & 7)) << 4);
    int w_off1 = col * 128 + ((((lg * 2) + 1 ) ^ (lr & 7)) << 4);

    // ---- A register-prefetch sources: row mf*16+lr, k-window lg*8 ----
    const char* bA0 = (const char*)midb + (size_t)lr * 2048 + lg * 16;
    const char* bA1 = bA0 + 16 * 2048;
    const char* bA2 = bA0 + 32 * 2048;
    const char* bA3 = bA0 + 48 * 2048;

    bf16x8 as_[3][4];                                  // depth-3 slots, static idx
    f32x4 acc0 = {}, acc1 = {}, acc2 = {}, acc3 = {};

    // ---- prologue: W slices 0..2 (DMA), A slices 0,1 (regs) ----
#pragma unroll
    for (int s = 0; s < 3; ++s) {
        GLL16(srcW1 + s * 128, dW1 + s * WSL);
        GLL16(srcW2 + s * 128, dW2 + s * WSL);
    }
    GLD(as_[0][0], bA0, 0);  GLD(as_[0][1], bA1, 0);
    GLD(as_[0][2], bA2, 0);  GLD(as_[0][3], bA3, 0);
    GLD(as_[1][0], bA0, 64); GLD(as_[1][1], bA1, 64);
    GLD(as_[1][2], bA2, 64); GLD(as_[1][3], bA3, 64);

#define VBODY(i, N, DOA, DOW) do {                                              \
        __builtin_amdgcn_sched_barrier(0);                                      \
        asm volatile("s_waitcnt vmcnt(" #N ")" ::: "memory");                   \
        __builtin_amdgcn_sched_barrier(0);                                      \
        __builtin_amdgcn_s_barrier();                                           \
        if (DOA) {                                                              \
            GLD(as_[((i)+2)%3][0], bA0, ((i)+2)*64);                            \
            GLD(as_[((i)+2)%3][1], bA1, ((i)+2)*64);                            \
            GLD(as_[((i)+2)%3][2], bA2, ((i)+2)*64);                            \
            GLD(as_[((i)+2)%3][3], bA3, ((i)+2)*64);                            \
        }                                                                       \
        if (DOW) {                                                              \
            GLL16(srcW1 + ((i)+3) * 128, dW1 + (((i)+3) & 3) * WSL);            \
            GLL16(srcW2 + ((i)+3) * 128, dW2 + (((i)+3) & 3) * WSL);            \
        }                                                                       \
        const char* wS = ldsW + ((i) & 3) * WSL;                                \
        f32x4 w0 = *(const f32x4*)(wS + w_off0);                                \
        f32x4 w1 = *(const f32x4*)(wS + w_off1);                                \
        bf16x8 bfr = pack_bf16(w0, w1);                                         \
        acc0 = __builtin_amdgcn_mfma_f32_16x16x32_bf16(as_[(i)%3][0], bfr, acc0, 0, 0, 0); \
        acc1 = __builtin_amdgcn_mfma_f32_16x16x32_bf16(as_[(i)%3][1], bfr, acc1, 0, 0, 0); \
        acc2 = __builtin_amdgcn_mfma_f32_16x16x32_bf16(as_[(i)%3][2], bfr, acc2, 0, 0, 0); \
        acc3 = __builtin_amdgcn_mfma_f32_16x16x32_bf16(as_[(i)%3][3], bfr, acc3, 0, 0, 0); \
    } while (0)

    VBODY(0, 4, 1, 1);  VBODY(1, 6, 1, 1);  VBODY(2, 8, 1, 1);  VBODY(3, 8, 1, 1);
    VBODY(4, 8, 1, 1);  VBODY(5, 8, 1, 1);  VBODY(6, 8, 1, 1);  VBODY(7, 8, 1, 1);
    VBODY(8, 8, 1, 1);  VBODY(9, 8, 1, 1);  VBODY(10, 8, 1, 1); VBODY(11, 8, 1, 1);
    VBODY(12, 8, 1, 1); VBODY(13, 8, 1, 1); VBODY(14, 8, 1, 1); VBODY(15, 8, 1, 1);
    VBODY(16, 8, 1, 1); VBODY(17, 8, 1, 1); VBODY(18, 8, 1, 1); VBODY(19, 8, 1, 1);
    VBODY(20, 8, 1, 1); VBODY(21, 8, 1, 1); VBODY(22, 8, 1, 1); VBODY(23, 8, 1, 1);
    VBODY(24, 8, 1, 1); VBODY(25, 8, 1, 1); VBODY(26, 8, 1, 1); VBODY(27, 8, 1, 1);
    VBODY(28, 8, 1, 1); VBODY(29, 8, 1, 0); VBODY(30, 6, 0, 0); VBODY(31, 0, 0, 0);
#undef VBODY

    int gcol = colBase + col;
    bool valid = gcol < V_;
    float bias = valid ? bv[valid ? gcol : V_ - 1] : 0.f;
    __shared__ float wsum[4][64];
    f32x4 accs[4] = {acc0, acc1, acc2, acc3};
#pragma unroll
    for (int mf = 0; mf < 4; ++mf) {
#pragma unroll
        for (int r = 0; r < 4; ++r) {
            int row = mf * 16 + lg * 4 + r;       // batch index
            float logit = accs[mf][r] + bias;
            logit = fminf(fmaxf(logit, -50.f), 50.f);
            float ev = valid ? __expf(logit - 50.f) : 0.f;
            if (valid) e[(size_t)row * VP + gcol] = ev;
            float s = ev;
            s += __shfl_xor(s, 1); s += __shfl_xor(s, 2);
            s += __shfl_xor(s, 4); s += __shfl_xor(s, 8);
            if (lr == 0) wsum[wave][row] = s;
        }
    }
    __syncthreads();
    if (threadIdx.x < 64) {
        int row = threadIdx.x;
        float t = wsum[0][row] + wsum[1][row] + wsum[2][row] + wsum[3][row];
        psum[(size_t)row * PSTR + blk] = t;
    }
}

// ---------------- Z reduction: zinv[b] = 1 / sum_blk psum ------------------
__global__ __launch_bounds__(256) void k_zred(const float* __restrict__ psum,
                                              float* __restrict__ zinv) {
    int b = blockIdx.x;
    int tid = threadIdx.x;
    float s = 0.f;
    for (int i = tid; i < NBLK; i += 256) s += psum[(size_t)b * PSTR + i];
#pragma unroll
    for (int m = 32; m >= 1; m >>= 1) s += __shfl_xor(s, m);
    __shared__ float r[4];
    int wave = tid >> 6, lane = tid & 63;
    if (lane == 0) r[wave] = s;
    __syncthreads();
    if (tid == 0) zinv[b] = 1.f / (r[0] + r[1] + r[2] + r[3]);
}

// ---------------- vocab_dist + generation part of final_dist ---------------
__global__ __launch_bounds__(256) void k_final(const float* __restrict__ e,
                                               const float* __restrict__ zinv,
                                               const float* __restrict__ pg,
                                               float* __restrict__ out0,
                                               float* __restrict__ out2) {
    int idx = blockIdx.x * 256 + threadIdx.x;     // < 64*50100
    if (idx >= B_ * EXTV) return;
    int b = idx / EXTV;
    int v = idx - b * EXTV;
    float o = 0.f;
    if (v < V_) {
        float vd = e[(size_t)b * VP + v] * zinv[b];
        out2[(size_t)b * V_ + v] = vd;
        o = pg[b] * vd;
    }
    out0[idx] = o;
}

// ---------------- copy-distribution scatter --------------------------------
__global__ __launch_bounds__(256) void k_scatter(const float* __restrict__ attn,
                                                 const int* __restrict__ sid,
                                                 const int* __restrict__ oov,
                                                 const float* __restrict__ pg,
                                                 float* __restrict__ out0) {
    int idx = blockIdx.x * 256 + threadIdx.x;
    if (idx >= B_ * S_) return;
    int b = idx / S_;
    int m = oov[idx];
    int tgt = (m >= 0) ? (V_ + m) : sid[idx];
    float w = (1.f - pg[b]) * attn[idx];
    atomicAdd(out0 + (size_t)b * EXTV + tgt, w);
}

extern "C" void kernel_launch(void* const* d_in, const int* in_sizes, int n_in,
                              void* d_out, int out_size, void* d_ws, size_t ws_size,
                              hipStream_t stream) {
    const float* dec  = (const float*)d_in[0];
    const float* ctx  = (const float*)d_in[1];
    const float* emb  = (const float*)d_in[2];
    const float* attn = (const float*)d_in[3];
    const int*   sid  = (const int*)d_in[4];
    const int*   oov  = (const int*)d_in[5];
    // d_in[6] = vocab_size (known statically = 50000)
    const float* Wm   = (const float*)d_in[7];
    const float* bm   = (const float*)d_in[8];
    const float* Wp   = (const float*)d_in[9];
    const float* bp   = (const float*)d_in[10];
    const float* Wv   = (const float*)d_in[11];
    const float* bv   = (const float*)d_in[12];

    float* out0 = (float*)d_out;                  // final_dist [64][50100]
    float* out1 = out0 + (size_t)B_ * EXTV;       // p_gen      [64]
    float* out2 = out1 + B_;                      // vocab_dist [64][50000]

    float*  e    = (float*)d_ws;                  // [64][VP]
    float*  psum = e + (size_t)B_ * VP;           // [64][PSTR]
    float*  zinv = psum + (size_t)B_ * PSTR;      // [64]
    float*  pg   = zinv + 64;                     // [64]
    float*  pmid = pg + 64;                       // [KCH][64][1024]
    __bf16* midb = (__bf16*)(pmid + (size_t)KCH * B_ * H_); // [64][1024]

    k_pgen<<<B_, 256, 0, stream>>>(dec, ctx, emb, Wp, bp, pg, out1);
    dim3 gmid(16, KCH);
    k_gemm_mid<<<gmid, 256, 0, stream>>>(dec, ctx, Wm, pmid);
    k_mid_reduce<<<(B_ * H_) / 256, 256, 0, stream>>>(pmid, bm, midb);
    k_gemm_vocab<<<NBLK, 256, 0, stream>>>((const __bf16*)midb, Wv, bv, e, psum);
    k_zred<<<B_, 256, 0, stream>>>(psum, zinv);
    k_final<<<(B_ * EXTV + 255) / 256, 256, 0, stream>>>(e, zinv, pg, out0, out2);
    k_scatter<<<(B_ * S_ + 255) / 256, 256, 0, stream>>>(attn, sid, oov, pg, out0);
}

// Round 10
// 75.158 us; speedup vs baseline: 2.0945x; 1.4176x over previous
//
#include <hip/hip_runtime.h>
#include <hip/hip_bf16.h>

#define B_   64
#define H_   1024
#define E_   512
#define V_   50000
#define S_   400
#define EXTV 50100        // V + 100
#define K2   2048         // 2H
#define KP   2560         // 2H + E
#define VP2  50048        // padded bf16-e row stride (mult of 16, >= 391*128)
#define NBLK2 391         // ceil(V / 128)
#define PSTR 400          // padded partial-sum stride (>= NBLK2)
#define KCH  16           // split-K chunks for mid GEMM

typedef float  f32x4  __attribute__((ext_vector_type(4)));
typedef __bf16 bf16x8 __attribute__((ext_vector_type(8)));

typedef __attribute__((address_space(1))) const void gas_t;
typedef __attribute__((address_space(3))) void las_t;
#define GLL16(g, l) __builtin_amdgcn_global_load_lds((gas_t*)(g), (las_t*)(l), 16, 0, 0)

static __device__ __forceinline__ bf16x8 pack_bf16(f32x4 a, f32x4 b) {
    bf16x8 r;
    r[0] = (__bf16)a[0]; r[1] = (__bf16)a[1]; r[2] = (__bf16)a[2]; r[3] = (__bf16)a[3];
    r[4] = (__bf16)b[0]; r[5] = (__bf16)b[1]; r[6] = (__bf16)b[2]; r[7] = (__bf16)b[3];
    return r;
}

// ---------------- p_gen: 64 dots of length 2560 -----------------------------
__global__ __launch_bounds__(256) void k_pgen(const float* __restrict__ dec,
                                              const float* __restrict__ ctx,
                                              const float* __restrict__ emb,
                                              const float* __restrict__ Wp,
                                              const float* __restrict__ bp,
                                              float* __restrict__ pg,
                                              float* __restrict__ out1) {
    int b = blockIdx.x;
    int tid = threadIdx.x;
    float s = 0.f;
    for (int k = tid; k < KP; k += 256) {
        float x;
        if (k < H_)          x = dec[b * H_ + k];
        else if (k < 2 * H_) x = ctx[b * H_ + k - H_];
        else                 x = emb[b * E_ + k - 2 * H_];
        s += x * Wp[k];
    }
#pragma unroll
    for (int m = 32; m >= 1; m >>= 1) s += __shfl_xor(s, m);
    __shared__ float r[4];
    int wave = tid >> 6, lane = tid & 63;
    if (lane == 0) r[wave] = s;
    __syncthreads();
    if (tid == 0) {
        float t = r[0] + r[1] + r[2] + r[3] + bp[0];
        float p = 1.f / (1.f + __expf(-t));
        pg[b]   = p;
        out1[b] = p;
    }
}

// ---------------- mid GEMM (split-K 16): M=64, N=1024, K=2048 ---------------
__global__ __launch_bounds__(256, 4) void k_gemm_mid(const float* __restrict__ dec,
                                                     const float* __restrict__ ctx,
                                                     const float* __restrict__ Wm,
                                                     float* __restrict__ pmid) {
    int nt   = blockIdx.x;             // 0..15  (h-tile of 64)
    int kc   = blockIdx.y;             // 0..15  (K-chunk of 128)
    int wave = threadIdx.x >> 6;
    int lane = threadIdx.x & 63;
    int lr   = lane & 15, lg = lane >> 4;
    int col  = nt * 64 + wave * 16 + lr;          // h index
    const float* xb   = (kc < 8) ? dec : ctx;
    int kbase         = (kc & 7) * 128;
    const float* wrow = Wm + (size_t)col * K2 + kc * 128 + lg * 8;
    const float* xrow = xb + (size_t)lr * H_ + kbase + lg * 8;

    f32x4 w0s[4], w1s[4];
#pragma unroll
    for (int p = 0; p < 4; ++p) {
        w0s[p] = *(const f32x4*)(wrow + p * 32);
        w1s[p] = *(const f32x4*)(wrow + p * 32 + 4);
    }
    f32x4 acc[4] = {};
#pragma unroll
    for (int i = 0; i < 4; ++i) {
        f32x4 a0[4], a1[4];
#pragma unroll
        for (int mf = 0; mf < 4; ++mf) {
            const float* xp = xrow + (size_t)(mf * 16) * H_ + i * 32;
            a0[mf] = *(const f32x4*)xp;
            a1[mf] = *(const f32x4*)(xp + 4);
        }
        bf16x8 bf = pack_bf16(w0s[i], w1s[i]);
#pragma unroll
        for (int mf = 0; mf < 4; ++mf) {
            bf16x8 af = pack_bf16(a0[mf], a1[mf]);
            acc[mf] = __builtin_amdgcn_mfma_f32_16x16x32_bf16(af, bf, acc[mf], 0, 0, 0);
        }
    }
#pragma unroll
    for (int mf = 0; mf < 4; ++mf)
#pragma unroll
        for (int r = 0; r < 4; ++r) {
            int row = mf * 16 + lg * 4 + r;       // batch index
            pmid[((size_t)kc * B_ + row) * H_ + col] = acc[mf][r];
        }
}

// ---------------- reduce split-K partials, bias, tanh, -> bf16 --------------
__global__ __launch_bounds__(256) void k_mid_reduce(const float* __restrict__ pmid,
                                                    const float* __restrict__ bm,
                                                    __bf16* __restrict__ midb) {
    int idx = blockIdx.x * 256 + threadIdx.x;     // 65536
    int h = idx & (H_ - 1);
    int m = idx >> 10;
    float s = bm[h];
#pragma unroll
    for (int kc = 0; kc < KCH; ++kc) s += pmid[((size_t)kc * B_ + m) * H_ + h];
    midb[idx] = (__bf16)tanhf(s);
}

// ---------------- big GEMM: e = exp(clip(mid @ Wv^T + bv) - 50) -------------
// N=128 per block (391 blocks). R3's proven pipeline structure, depth-3:
//  * per K=32 slice: W = 16KB (each wave stages ITS OWN 32 cols, 4 GLL16) +
//    A = 4KB shared (R3-verbatim cooperative staging, 1 GLL16/wave).
//    A share of staged bytes drops 33% -> 20%; barrier count halves.
//  * vmcnt(5) retires exactly slice i (5 instr/slice/wave); 2 slices in flight.
//  * e stored bf16 (halves softmax-pass traffic).
__global__ __launch_bounds__(256, 2) void k_gemm_vocab(const __bf16* __restrict__ midb,
                                                       const float* __restrict__ Wv,
                                                       const float* __restrict__ bv,
                                                       __bf16* __restrict__ e,
                                                       float* __restrict__ psum) {
    __shared__ __align__(16) char ldsW[3 * 16384];   // 48 KB: [buf][col 0..127][128B]
    __shared__ __align__(16) char ldsA[3 * 4096];    // 12 KB: [buf][row 0..63][64B]
    __shared__ float wsum[4][64];

    int tid  = threadIdx.x;
    int wave = tid >> 6;
    int lane = tid & 63;
    int lr   = lane & 15, lg = lane >> 4;
    int blk  = blockIdx.x;
    int colBase = blk * 128;

    // ---- W staging sources: instr j covers cols wave*32 + j*8 .. +7 --------
    const char* srcW[4];
#pragma unroll
    for (int j = 0; j < 4; ++j) {
        int c = colBase + wave * 32 + j * 8 + (lane >> 3);
        if (c >= V_) c = V_ - 1;
        int t = (lane & 7) ^ (c & 7);                  // swizzled source granule
        srcW[j] = (const char*)Wv + (size_t)c * 4096 + t * 16;
    }
    // ---- A staging source (R3-verbatim): wave stages rows wave*16..+15 -----
    int arow = wave * 16 + (lane >> 2);
    int asw  = (((lane & 3) ^ ((lane >> 3) & 3)) << 4);
    const char* srcA = (const char*)midb + (size_t)arow * 2048 + asw;

    // ---- LDS read offsets ----
    int colL0 = wave * 32 + lr;                        // cf=0 block-local col
    int colL1 = colL0 + 16;                            // cf=1
    int w00 = colL0 * 128 + ((((lg * 2)    ) ^ (colL0 & 7)) << 4);
    int w01 = colL0 * 128 + ((((lg * 2) + 1) ^ (colL0 & 7)) << 4);
    int w10 = colL1 * 128 + ((((lg * 2)    ) ^ (colL1 & 7)) << 4);
    int w11 = colL1 * 128 + ((((lg * 2) + 1) ^ (colL1 & 7)) << 4);
    int phiA  = (lr >> 1) & 3;
    int aoff0 = (0 * 16 + lr) * 64 + ((lg ^ phiA) << 4);
    int aoff1 = (1 * 16 + lr) * 64 + ((lg ^ phiA) << 4);
    int aoff2 = (2 * 16 + lr) * 64 + ((lg ^ phiA) << 4);
    int aoff3 = (3 * 16 + lr) * 64 + ((lg ^ phiA) << 4);

    f32x4 acc00 = {}, acc01 = {}, acc02 = {}, acc03 = {};   // cf=0, m=0..3
    f32x4 acc10 = {}, acc11 = {}, acc12 = {}, acc13 = {};   // cf=1

#define STAGE(s) do {                                                           \
        char* _bW = ldsW + ((s) % 3) * 16384 + wave * 4096;                     \
        char* _bA = ldsA + ((s) % 3) * 4096 + wave * 1024;                      \
        GLL16(srcW[0] + (s) * 128, _bW);                                        \
        GLL16(srcW[1] + (s) * 128, _bW + 1024);                                 \
        GLL16(srcW[2] + (s) * 128, _bW + 2048);                                 \
        GLL16(srcW[3] + (s) * 128, _bW + 3072);                                 \
        GLL16(srcA    + (s) * 64,  _bA);                                        \
    } while (0)

    // ---- prologue: slices 0,1 in flight (10 instr) ----
    STAGE(0);
    STAGE(1);

#define VBODY(i, N, DOW) do {                                                   \
        __builtin_amdgcn_sched_barrier(0);                                      \
        asm volatile("s_waitcnt vmcnt(" #N ")" ::: "memory");                   \
        __builtin_amdgcn_sched_barrier(0);                                      \
        __builtin_amdgcn_s_barrier();                                           \
        if (DOW) STAGE((i) + 2);                                                \
        const char* wS = ldsW + ((i) % 3) * 16384;                              \
        const char* aS = ldsA + ((i) % 3) * 4096;                               \
        f32x4 x00 = *(const f32x4*)(wS + w00);                                  \
        f32x4 x01 = *(const f32x4*)(wS + w01);                                  \
        f32x4 x10 = *(const f32x4*)(wS + w10);                                  \
        f32x4 x11 = *(const f32x4*)(wS + w11);                                  \
        bf16x8 bf0 = pack_bf16(x00, x01);                                       \
        bf16x8 bf1 = pack_bf16(x10, x11);                                       \
        bf16x8 af0 = *(const bf16x8*)(aS + aoff0);                              \
        bf16x8 af1 = *(const bf16x8*)(aS + aoff1);                              \
        bf16x8 af2 = *(const bf16x8*)(aS + aoff2);                              \
        bf16x8 af3 = *(const bf16x8*)(aS + aoff3);                              \
        acc00 = __builtin_amdgcn_mfma_f32_16x16x32_bf16(af0, bf0, acc00, 0, 0, 0); \
        acc01 = __builtin_amdgcn_mfma_f32_16x16x32_bf16(af1, bf0, acc01, 0, 0, 0); \
        acc02 = __builtin_amdgcn_mfma_f32_16x16x32_bf16(af2, bf0, acc02, 0, 0, 0); \
        acc03 = __builtin_amdgcn_mfma_f32_16x16x32_bf16(af3, bf0, acc03, 0, 0, 0); \
        acc10 = __builtin_amdgcn_mfma_f32_16x16x32_bf16(af0, bf1, acc10, 0, 0, 0); \
        acc11 = __builtin_amdgcn_mfma_f32_16x16x32_bf16(af1, bf1, acc11, 0, 0, 0); \
        acc12 = __builtin_amdgcn_mfma_f32_16x16x32_bf16(af2, bf1, acc12, 0, 0, 0); \
        acc13 = __builtin_amdgcn_mfma_f32_16x16x32_bf16(af3, bf1, acc13, 0, 0, 0); \
    } while (0)

    VBODY(0, 5, 1);  VBODY(1, 5, 1);  VBODY(2, 5, 1);  VBODY(3, 5, 1);
    VBODY(4, 5, 1);  VBODY(5, 5, 1);  VBODY(6, 5, 1);  VBODY(7, 5, 1);
    VBODY(8, 5, 1);  VBODY(9, 5, 1);  VBODY(10, 5, 1); VBODY(11, 5, 1);
    VBODY(12, 5, 1); VBODY(13, 5, 1); VBODY(14, 5, 1); VBODY(15, 5, 1);
    VBODY(16, 5, 1); VBODY(17, 5, 1); VBODY(18, 5, 1); VBODY(19, 5, 1);
    VBODY(20, 5, 1); VBODY(21, 5, 1); VBODY(22, 5, 1); VBODY(23, 5, 1);
    VBODY(24, 5, 1); VBODY(25, 5, 1); VBODY(26, 5, 1); VBODY(27, 5, 1);
    VBODY(28, 5, 1); VBODY(29, 5, 1); VBODY(30, 5, 0); VBODY(31, 0, 0);
#undef VBODY
#undef STAGE

    // ---- epilogue ----
    int gc0 = colBase + colL0;
    int gc1 = colBase + colL1;
    bool v0 = gc0 < V_, v1 = gc1 < V_;
    float b0 = v0 ? bv[gc0] : 0.f;
    float b1 = v1 ? bv[gc1] : 0.f;
    f32x4 accA[4] = {acc00, acc01, acc02, acc03};
    f32x4 accB[4] = {acc10, acc11, acc12, acc13};
#pragma unroll
    for (int mf = 0; mf < 4; ++mf) {
#pragma unroll
        for (int r = 0; r < 4; ++r) {
            int row = mf * 16 + lg * 4 + r;       // batch index
            float l0 = fminf(fmaxf(accA[mf][r] + b0, -50.f), 50.f);
            float l1 = fminf(fmaxf(accB[mf][r] + b1, -50.f), 50.f);
            float e0 = v0 ? __expf(l0 - 50.f) : 0.f;
            float e1 = v1 ? __expf(l1 - 50.f) : 0.f;
            if (v0) e[(size_t)row * VP2 + gc0] = (__bf16)e0;
            if (v1) e[(size_t)row * VP2 + gc1] = (__bf16)e1;
            float s = e0 + e1;
            s += __shfl_xor(s, 1); s += __shfl_xor(s, 2);
            s += __shfl_xor(s, 4); s += __shfl_xor(s, 8);
            if (lr == 0) wsum[wave][row] = s;
        }
    }
    __syncthreads();
    if (threadIdx.x < 64) {
        int row = threadIdx.x;
        float t = wsum[0][row] + wsum[1][row] + wsum[2][row] + wsum[3][row];
        psum[(size_t)row * PSTR + blk] = t;
    }
}

// ---------------- Z reduction: zinv[b] = 1 / sum_blk psum ------------------
__global__ __launch_bounds__(256) void k_zred(const float* __restrict__ psum,
                                              float* __restrict__ zinv) {
    int b = blockIdx.x;
    int tid = threadIdx.x;
    float s = 0.f;
    for (int i = tid; i < NBLK2; i += 256) s += psum[(size_t)b * PSTR + i];
#pragma unroll
    for (int m = 32; m >= 1; m >>= 1) s += __shfl_xor(s, m);
    __shared__ float r[4];
    int wave = tid >> 6, lane = tid & 63;
    if (lane == 0) r[wave] = s;
    __syncthreads();
    if (tid == 0) zinv[b] = 1.f / (r[0] + r[1] + r[2] + r[3]);
}

// ---------------- vocab_dist + generation part of final_dist ---------------
__global__ __launch_bounds__(256) void k_final(const __bf16* __restrict__ e,
                                               const float* __restrict__ zinv,
                                               const float* __restrict__ pg,
                                               float* __restrict__ out0,
                                               float* __restrict__ out2) {
    int idx = blockIdx.x * 256 + threadIdx.x;     // < 64*50100
    if (idx >= B_ * EXTV) return;
    int b = idx / EXTV;
    int v = idx - b * EXTV;
    float o = 0.f;
    if (v < V_) {
        float vd = (float)e[(size_t)b * VP2 + v] * zinv[b];
        out2[(size_t)b * V_ + v] = vd;
        o = pg[b] * vd;
    }
    out0[idx] = o;
}

// ---------------- copy-distribution scatter --------------------------------
__global__ __launch_bounds__(256) void k_scatter(const float* __restrict__ attn,
                                                 const int* __restrict__ sid,
                                                 const int* __restrict__ oov,
                                                 const float* __restrict__ pg,
                                                 float* __restrict__ out0) {
    int idx = blockIdx.x * 256 + threadIdx.x;
    if (idx >= B_ * S_) return;
    int b = idx / S_;
    int m = oov[idx];
    int tgt = (m >= 0) ? (V_ + m) : sid[idx];
    float w = (1.f - pg[b]) * attn[idx];
    atomicAdd(out0 + (size_t)b * EXTV + tgt, w);
}

extern "C" void kernel_launch(void* const* d_in, const int* in_sizes, int n_in,
                              void* d_out, int out_size, void* d_ws, size_t ws_size,
                              hipStream_t stream) {
    const float* dec  = (const float*)d_in[0];
    const float* ctx  = (const float*)d_in[1];
    const float* emb  = (const float*)d_in[2];
    const float* attn = (const float*)d_in[3];
    const int*   sid  = (const int*)d_in[4];
    const int*   oov  = (const int*)d_in[5];
    // d_in[6] = vocab_size (known statically = 50000)
    const float* Wm   = (const float*)d_in[7];
    const float* bm   = (const float*)d_in[8];
    const float* Wp   = (const float*)d_in[9];
    const float* bp   = (const float*)d_in[10];
    const float* Wv   = (const float*)d_in[11];
    const float* bv   = (const float*)d_in[12];

    float* out0 = (float*)d_out;                  // final_dist [64][50100]
    float* out1 = out0 + (size_t)B_ * EXTV;       // p_gen      [64]
    float* out2 = out1 + B_;                      // vocab_dist [64][50000]

    __bf16* e    = (__bf16*)d_ws;                            // [64][VP2] bf16
    float*  psum = (float*)((char*)d_ws + (size_t)B_ * VP2 * 2); // [64][PSTR]
    float*  zinv = psum + (size_t)B_ * PSTR;      // [64]
    float*  pg   = zinv + 64;                     // [64]
    float*  pmid = pg + 64;                       // [KCH][64][1024]
    __bf16* midb = (__bf16*)(pmid + (size_t)KCH * B_ * H_); // [64][1024]

    k_pgen<<<B_, 256, 0, stream>>>(dec, ctx, emb, Wp, bp, pg, out1);
    dim3 gmid(16, KCH);
    k_gemm_mid<<<gmid, 256, 0, stream>>>(dec, ctx, Wm, pmid);
    k_mid_reduce<<<(B_ * H_) / 256, 256, 0, stream>>>(pmid, bm, midb);
    k_gemm_vocab<<<NBLK2, 256, 0, stream>>>((const __bf16*)midb, Wv, bv, e, psum);
    k_zred<<<B_, 256, 0, stream>>>(psum, zinv);
    k_final<<<(B_ * EXTV + 255) / 256, 256, 0, stream>>>(e, zinv, pg, out0, out2);
    k_scatter<<<(B_ * S_ + 255) / 256, 256, 0, stream>>>(attn, sid, oov, pg, out0);
}

// Round 11
// 64.515 us; speedup vs baseline: 2.4400x; 1.1650x over previous
//
#include <hip/hip_runtime.h>
#include <hip/hip_bf16.h>

#define B_   64
#define H_   1024
#define E_   512
#define V_   50000
#define S_   400
#define EXTV 50100        // V + 100
#define K2   2048         // 2H
#define KP   2560         // 2H + E
#define VP2  50048        // padded bf16-e row stride (mult of 16, >= 391*128)
#define NBLK2 391         // ceil(V / 128)
#define PSTR 400          // padded partial-sum stride (>= NBLK2)
#define KCH  16           // split-K chunks for mid GEMM

typedef float  f32x4  __attribute__((ext_vector_type(4)));
typedef __bf16 bf16x8 __attribute__((ext_vector_type(8)));
typedef unsigned short u16x4 __attribute__((ext_vector_type(4)));

typedef __attribute__((address_space(1))) const void gas_t;
typedef __attribute__((address_space(3))) void las_t;
#define GLL16(g, l) __builtin_amdgcn_global_load_lds((gas_t*)(g), (las_t*)(l), 16, 0, 0)

static __device__ __forceinline__ bf16x8 pack_bf16(f32x4 a, f32x4 b) {
    bf16x8 r;
    r[0] = (__bf16)a[0]; r[1] = (__bf16)a[1]; r[2] = (__bf16)a[2]; r[3] = (__bf16)a[3];
    r[4] = (__bf16)b[0]; r[5] = (__bf16)b[1]; r[6] = (__bf16)b[2]; r[7] = (__bf16)b[3];
    return r;
}

// ---------------- p_gen: 64 dots of length 2560 -----------------------------
__global__ __launch_bounds__(256) void k_pgen(const float* __restrict__ dec,
                                              const float* __restrict__ ctx,
                                              const float* __restrict__ emb,
                                              const float* __restrict__ Wp,
                                              const float* __restrict__ bp,
                                              float* __restrict__ pg,
                                              float* __restrict__ out1) {
    int b = blockIdx.x;
    int tid = threadIdx.x;
    float s = 0.f;
    for (int k = tid; k < KP; k += 256) {
        float x;
        if (k < H_)          x = dec[b * H_ + k];
        else if (k < 2 * H_) x = ctx[b * H_ + k - H_];
        else                 x = emb[b * E_ + k - 2 * H_];
        s += x * Wp[k];
    }
#pragma unroll
    for (int m = 32; m >= 1; m >>= 1) s += __shfl_xor(s, m);
    __shared__ float r[4];
    int wave = tid >> 6, lane = tid & 63;
    if (lane == 0) r[wave] = s;
    __syncthreads();
    if (tid == 0) {
        float t = r[0] + r[1] + r[2] + r[3] + bp[0];
        float p = 1.f / (1.f + __expf(-t));
        pg[b]   = p;
        out1[b] = p;
    }
}

// ---------------- mid GEMM (split-K 16): M=64, N=1024, K=2048 ---------------
__global__ __launch_bounds__(256, 4) void k_gemm_mid(const float* __restrict__ dec,
                                                     const float* __restrict__ ctx,
                                                     const float* __restrict__ Wm,
                                                     float* __restrict__ pmid) {
    int nt   = blockIdx.x;             // 0..15  (h-tile of 64)
    int kc   = blockIdx.y;             // 0..15  (K-chunk of 128)
    int wave = threadIdx.x >> 6;
    int lane = threadIdx.x & 63;
    int lr   = lane & 15, lg = lane >> 4;
    int col  = nt * 64 + wave * 16 + lr;          // h index
    const float* xb   = (kc < 8) ? dec : ctx;
    int kbase         = (kc & 7) * 128;
    const float* wrow = Wm + (size_t)col * K2 + kc * 128 + lg * 8;
    const float* xrow = xb + (size_t)lr * H_ + kbase + lg * 8;

    f32x4 w0s[4], w1s[4];
#pragma unroll
    for (int p = 0; p < 4; ++p) {
        w0s[p] = *(const f32x4*)(wrow + p * 32);
        w1s[p] = *(const f32x4*)(wrow + p * 32 + 4);
    }
    f32x4 acc[4] = {};
#pragma unroll
    for (int i = 0; i < 4; ++i) {
        f32x4 a0[4], a1[4];
#pragma unroll
        for (int mf = 0; mf < 4; ++mf) {
            const float* xp = xrow + (size_t)(mf * 16) * H_ + i * 32;
            a0[mf] = *(const f32x4*)xp;
            a1[mf] = *(const f32x4*)(xp + 4);
        }
        bf16x8 bf = pack_bf16(w0s[i], w1s[i]);
#pragma unroll
        for (int mf = 0; mf < 4; ++mf) {
            bf16x8 af = pack_bf16(a0[mf], a1[mf]);
            acc[mf] = __builtin_amdgcn_mfma_f32_16x16x32_bf16(af, bf, acc[mf], 0, 0, 0);
        }
    }
#pragma unroll
    for (int mf = 0; mf < 4; ++mf)
#pragma unroll
        for (int r = 0; r < 4; ++r) {
            int row = mf * 16 + lg * 4 + r;       // batch index
            pmid[((size_t)kc * B_ + row) * H_ + col] = acc[mf][r];
        }
}

// ---------------- reduce split-K partials, bias, tanh, -> bf16 --------------
__global__ __launch_bounds__(256) void k_mid_reduce(const float* __restrict__ pmid,
                                                    const float* __restrict__ bm,
                                                    __bf16* __restrict__ midb) {
    int idx = blockIdx.x * 256 + threadIdx.x;     // 65536
    int h = idx & (H_ - 1);
    int m = idx >> 10;
    float s = bm[h];
#pragma unroll
    for (int kc = 0; kc < KCH; ++kc) s += pmid[((size_t)kc * B_ + m) * H_ + h];
    midb[idx] = (__bf16)tanhf(s);
}

// ---------------- big GEMM: e = exp(clip(mid @ Wv^T + bv) - 50) -------------
// (unchanged from R10 — timed-proven 75.2 structure)
__global__ __launch_bounds__(256, 2) void k_gemm_vocab(const __bf16* __restrict__ midb,
                                                       const float* __restrict__ Wv,
                                                       const float* __restrict__ bv,
                                                       __bf16* __restrict__ e,
                                                       float* __restrict__ psum) {
    __shared__ __align__(16) char ldsW[3 * 16384];   // 48 KB: [buf][col 0..127][128B]
    __shared__ __align__(16) char ldsA[3 * 4096];    // 12 KB: [buf][row 0..63][64B]
    __shared__ float wsum[4][64];

    int tid  = threadIdx.x;
    int wave = tid >> 6;
    int lane = tid & 63;
    int lr   = lane & 15, lg = lane >> 4;
    int blk  = blockIdx.x;
    int colBase = blk * 128;

    const char* srcW[4];
#pragma unroll
    for (int j = 0; j < 4; ++j) {
        int c = colBase + wave * 32 + j * 8 + (lane >> 3);
        if (c >= V_) c = V_ - 1;
        int t = (lane & 7) ^ (c & 7);                  // swizzled source granule
        srcW[j] = (const char*)Wv + (size_t)c * 4096 + t * 16;
    }
    int arow = wave * 16 + (lane >> 2);
    int asw  = (((lane & 3) ^ ((lane >> 3) & 3)) << 4);
    const char* srcA = (const char*)midb + (size_t)arow * 2048 + asw;

    int colL0 = wave * 32 + lr;                        // cf=0 block-local col
    int colL1 = colL0 + 16;                            // cf=1
    int w00 = colL0 * 128 + ((((lg * 2)    ) ^ (colL0 & 7)) << 4);
    int w01 = colL0 * 128 + ((((lg * 2) + 1) ^ (colL0 & 7)) << 4);
    int w10 = colL1 * 128 + ((((lg * 2)    ) ^ (colL1 & 7)) << 4);
    int w11 = colL1 * 128 + ((((lg * 2) + 1) ^ (colL1 & 7)) << 4);
    int phiA  = (lr >> 1) & 3;
    int aoff0 = (0 * 16 + lr) * 64 + ((lg ^ phiA) << 4);
    int aoff1 = (1 * 16 + lr) * 64 + ((lg ^ phiA) << 4);
    int aoff2 = (2 * 16 + lr) * 64 + ((lg ^ phiA) << 4);
    int aoff3 = (3 * 16 + lr) * 64 + ((lg ^ phiA) << 4);

    f32x4 acc00 = {}, acc01 = {}, acc02 = {}, acc03 = {};   // cf=0, m=0..3
    f32x4 acc10 = {}, acc11 = {}, acc12 = {}, acc13 = {};   // cf=1

#define STAGE(s) do {                                                           \
        char* _bW = ldsW + ((s) % 3) * 16384 + wave * 4096;                     \
        char* _bA = ldsA + ((s) % 3) * 4096 + wave * 1024;                      \
        GLL16(srcW[0] + (s) * 128, _bW);                                        \
        GLL16(srcW[1] + (s) * 128, _bW + 1024);                                 \
        GLL16(srcW[2] + (s) * 128, _bW + 2048);                                 \
        GLL16(srcW[3] + (s) * 128, _bW + 3072);                                 \
        GLL16(srcA    + (s) * 64,  _bA);                                        \
    } while (0)

    STAGE(0);
    STAGE(1);

#define VBODY(i, N, DOW) do {                                                   \
        __builtin_amdgcn_sched_barrier(0);                                      \
        asm volatile("s_waitcnt vmcnt(" #N ")" ::: "memory");                   \
        __builtin_amdgcn_sched_barrier(0);                                      \
        __builtin_amdgcn_s_barrier();                                           \
        if (DOW) STAGE((i) + 2);                                                \
        const char* wS = ldsW + ((i) % 3) * 16384;                              \
        const char* aS = ldsA + ((i) % 3) * 4096;                               \
        f32x4 x00 = *(const f32x4*)(wS + w00);                                  \
        f32x4 x01 = *(const f32x4*)(wS + w01);                                  \
        f32x4 x10 = *(const f32x4*)(wS + w10);                                  \
        f32x4 x11 = *(const f32x4*)(wS + w11);                                  \
        bf16x8 bf0 = pack_bf16(x00, x01);                                       \
        bf16x8 bf1 = pack_bf16(x10, x11);                                       \
        bf16x8 af0 = *(const bf16x8*)(aS + aoff0);                              \
        bf16x8 af1 = *(const bf16x8*)(aS + aoff1);                              \
        bf16x8 af2 = *(const bf16x8*)(aS + aoff2);                              \
        bf16x8 af3 = *(const bf16x8*)(aS + aoff3);                              \
        acc00 = __builtin_amdgcn_mfma_f32_16x16x32_bf16(af0, bf0, acc00, 0, 0, 0); \
        acc01 = __builtin_amdgcn_mfma_f32_16x16x32_bf16(af1, bf0, acc01, 0, 0, 0); \
        acc02 = __builtin_amdgcn_mfma_f32_16x16x32_bf16(af2, bf0, acc02, 0, 0, 0); \
        acc03 = __builtin_amdgcn_mfma_f32_16x16x32_bf16(af3, bf0, acc03, 0, 0, 0); \
        acc10 = __builtin_amdgcn_mfma_f32_16x16x32_bf16(af0, bf1, acc10, 0, 0, 0); \
        acc11 = __builtin_amdgcn_mfma_f32_16x16x32_bf16(af1, bf1, acc11, 0, 0, 0); \
        acc12 = __builtin_amdgcn_mfma_f32_16x16x32_bf16(af2, bf1, acc12, 0, 0, 0); \
        acc13 = __builtin_amdgcn_mfma_f32_16x16x32_bf16(af3, bf1, acc13, 0, 0, 0); \
    } while (0)

    VBODY(0, 5, 1);  VBODY(1, 5, 1);  VBODY(2, 5, 1);  VBODY(3, 5, 1);
    VBODY(4, 5, 1);  VBODY(5, 5, 1);  VBODY(6, 5, 1);  VBODY(7, 5, 1);
    VBODY(8, 5, 1);  VBODY(9, 5, 1);  VBODY(10, 5, 1); VBODY(11, 5, 1);
    VBODY(12, 5, 1); VBODY(13, 5, 1); VBODY(14, 5, 1); VBODY(15, 5, 1);
    VBODY(16, 5, 1); VBODY(17, 5, 1); VBODY(18, 5, 1); VBODY(19, 5, 1);
    VBODY(20, 5, 1); VBODY(21, 5, 1); VBODY(22, 5, 1); VBODY(23, 5, 1);
    VBODY(24, 5, 1); VBODY(25, 5, 1); VBODY(26, 5, 1); VBODY(27, 5, 1);
    VBODY(28, 5, 1); VBODY(29, 5, 1); VBODY(30, 5, 0); VBODY(31, 0, 0);
#undef VBODY
#undef STAGE

    int gc0 = colBase + colL0;
    int gc1 = colBase + colL1;
    bool v0 = gc0 < V_, v1 = gc1 < V_;
    float b0 = v0 ? bv[gc0] : 0.f;
    float b1 = v1 ? bv[gc1] : 0.f;
    f32x4 accA[4] = {acc00, acc01, acc02, acc03};
    f32x4 accB[4] = {acc10, acc11, acc12, acc13};
#pragma unroll
    for (int mf = 0; mf < 4; ++mf) {
#pragma unroll
        for (int r = 0; r < 4; ++r) {
            int row = mf * 16 + lg * 4 + r;       // batch index
            float l0 = fminf(fmaxf(accA[mf][r] + b0, -50.f), 50.f);
            float l1 = fminf(fmaxf(accB[mf][r] + b1, -50.f), 50.f);
            float e0 = v0 ? __expf(l0 - 50.f) : 0.f;
            float e1 = v1 ? __expf(l1 - 50.f) : 0.f;
            if (v0) e[(size_t)row * VP2 + gc0] = (__bf16)e0;
            if (v1) e[(size_t)row * VP2 + gc1] = (__bf16)e1;
            float s = e0 + e1;
            s += __shfl_xor(s, 1); s += __shfl_xor(s, 2);
            s += __shfl_xor(s, 4); s += __shfl_xor(s, 8);
            if (lr == 0) wsum[wave][row] = s;
        }
    }
    __syncthreads();
    if (threadIdx.x < 64) {
        int row = threadIdx.x;
        float t = wsum[0][row] + wsum[1][row] + wsum[2][row] + wsum[3][row];
        psum[(size_t)row * PSTR + blk] = t;
    }
}

// ------- fused Z-reduce + normalize + outputs (vectorized x4) ---------------
// grid 512 = 64 b x 8 sub. Every block recomputes zinv[b] from psum (1.5 KB,
// L2-hot), then writes its 1/8 of row b: out2 = e*zinv, out0 = pg*out2.
// sub==7 blocks also zero the 100-wide OOV pad of out0.
__global__ __launch_bounds__(256) void k_finalz(const __bf16* __restrict__ e,
                                                const float* __restrict__ psum,
                                                const float* __restrict__ pg,
                                                float* __restrict__ out0,
                                                float* __restrict__ out2) {
    int b   = blockIdx.x >> 3;
    int sub = blockIdx.x & 7;
    int tid = threadIdx.x;

    // ---- zinv[b]: all threads cooperate, result broadcast via LDS ----
    float s = 0.f;
    for (int i = tid; i < NBLK2; i += 256) s += psum[(size_t)b * PSTR + i];
#pragma unroll
    for (int m = 32; m >= 1; m >>= 1) s += __shfl_xor(s, m);
    __shared__ float r[4];
    __shared__ float zsh;
    int wave = tid >> 6, lane = tid & 63;
    if (lane == 0) r[wave] = s;
    __syncthreads();
    if (tid == 0) zsh = 1.f / (r[0] + r[1] + r[2] + r[3]);
    __syncthreads();
    float zinv = zsh;
    float p = pg[b];

    // ---- vectorized normalize: 12500 vec4 groups per b, 1563 per sub ----
    int v4beg = sub * 1563;
    int v4end = v4beg + 1563;
    if (v4end > 12500) v4end = 12500;
    const u16x4* erow = (const u16x4*)(e + (size_t)b * VP2);
    f32x4* o0 = (f32x4*)(out0 + (size_t)b * EXTV);
    f32x4* o2 = (f32x4*)(out2 + (size_t)b * V_);
    for (int v4 = v4beg + tid; v4 < v4end; v4 += 256) {
        u16x4 u = erow[v4];
        f32x4 vd;
        vd[0] = __uint_as_float((unsigned)u[0] << 16) * zinv;
        vd[1] = __uint_as_float((unsigned)u[1] << 16) * zinv;
        vd[2] = __uint_as_float((unsigned)u[2] << 16) * zinv;
        vd[3] = __uint_as_float((unsigned)u[3] << 16) * zinv;
        o2[v4] = vd;
        f32x4 g;
        g[0] = p * vd[0]; g[1] = p * vd[1]; g[2] = p * vd[2]; g[3] = p * vd[3];
        o0[v4] = g;
    }
    // ---- OOV pad of out0: zero (scatter adds on top afterwards) ----
    if (sub == 7 && tid < 100) out0[(size_t)b * EXTV + V_ + tid] = 0.f;
}

// ---------------- copy-distribution scatter --------------------------------
__global__ __launch_bounds__(256) void k_scatter(const float* __restrict__ attn,
                                                 const int* __restrict__ sid,
                                                 const int* __restrict__ oov,
                                                 const float* __restrict__ pg,
                                                 float* __restrict__ out0) {
    int idx = blockIdx.x * 256 + threadIdx.x;
    if (idx >= B_ * S_) return;
    int b = idx / S_;
    int m = oov[idx];
    int tgt = (m >= 0) ? (V_ + m) : sid[idx];
    float w = (1.f - pg[b]) * attn[idx];
    atomicAdd(out0 + (size_t)b * EXTV + tgt, w);
}

extern "C" void kernel_launch(void* const* d_in, const int* in_sizes, int n_in,
                              void* d_out, int out_size, void* d_ws, size_t ws_size,
                              hipStream_t stream) {
    const float* dec  = (const float*)d_in[0];
    const float* ctx  = (const float*)d_in[1];
    const float* emb  = (const float*)d_in[2];
    const float* attn = (const float*)d_in[3];
    const int*   sid  = (const int*)d_in[4];
    const int*   oov  = (const int*)d_in[5];
    // d_in[6] = vocab_size (known statically = 50000)
    const float* Wm   = (const float*)d_in[7];
    const float* bm   = (const float*)d_in[8];
    const float* Wp   = (const float*)d_in[9];
    const float* bp   = (const float*)d_in[10];
    const float* Wv   = (const float*)d_in[11];
    const float* bv   = (const float*)d_in[12];

    float* out0 = (float*)d_out;                  // final_dist [64][50100]
    float* out1 = out0 + (size_t)B_ * EXTV;       // p_gen      [64]
    float* out2 = out1 + B_;                      // vocab_dist [64][50000]

    __bf16* e    = (__bf16*)d_ws;                            // [64][VP2] bf16
    float*  psum = (float*)((char*)d_ws + (size_t)B_ * VP2 * 2); // [64][PSTR]
    float*  pg   = psum + (size_t)B_ * PSTR;      // [64]
    float*  pmid = pg + 64;                       // [KCH][64][1024]
    __bf16* midb = (__bf16*)(pmid + (size_t)KCH * B_ * H_); // [64][1024]

    k_pgen<<<B_, 256, 0, stream>>>(dec, ctx, emb, Wp, bp, pg, out1);
    dim3 gmid(16, KCH);
    k_gemm_mid<<<gmid, 256, 0, stream>>>(dec, ctx, Wm, pmid);
    k_mid_reduce<<<(B_ * H_) / 256, 256, 0, stream>>>(pmid, bm, midb);
    k_gemm_vocab<<<NBLK2, 256, 0, stream>>>((const __bf16*)midb, Wv, bv, e, psum);
    k_finalz<<<B_ * 8, 256, 0, stream>>>((const __bf16*)e, psum, pg, out0, out2);
    k_scatter<<<(B_ * S_ + 255) / 256, 256, 0, stream>>>(attn, sid, oov, pg, out0);
}